// Round 6
// baseline (111.295 us; speedup 1.0000x reference)
//
#include <hip/hip_runtime.h>
#include <math.h>

// SegmentCausalCrossAttentionFlex on MI355X (gfx950)
// B=2, LQ=4096, LK=512, Q_DIM=KV_DIM=D_ATTN=1024, H=16, HD=64, LOOKBACK=4
// R6: LDS-intensity-optimized GEMM core. BM=256,BN=128,BK=32; 4 waves (2x2),
// wave-tile 128x64 (8x4 frags, 128 acc VGPR); 3 LDS buffers (72KB -> 2
// blocks/CU); 2-phase counted vmcnt(6) (6 gload_lds/thread/stage).
// Cuts LDS bytes/MFMA 768 -> 562 and doubles MFMA per CU-K-step.

typedef unsigned short u16;
typedef __attribute__((ext_vector_type(8))) short bhalf8;   // 8 x bf16 (MFMA A/B frag)
typedef __attribute__((ext_vector_type(4))) float fvec4;    // MFMA C/D frag

__device__ __forceinline__ u16 f2bf(float f) {
  unsigned u = __float_as_uint(f);
  u += 0x7fffu + ((u >> 16) & 1u);      // round-to-nearest-even
  return (u16)(u >> 16);
}
__device__ __forceinline__ float bf2f(u16 h) {
  return __uint_as_float(((unsigned)h) << 16);
}

// ---------------------------------------------------------------------------
// Fused preprocessing (unchanged from R3).
__global__ __launch_bounds__(256) void prep_kernel(
    const float* __restrict__ Wq, const float* __restrict__ Wkv,
    const float* __restrict__ Wo, u16* __restrict__ WqT,
    u16* __restrict__ WkvT, u16* __restrict__ WoT,
    const float* __restrict__ q, u16* __restrict__ qb,
    const float* __restrict__ kv, u16* __restrict__ kvb,
    float2* __restrict__ csT) {
  const int bid = blockIdx.x;
  if (bid < 4096) {
    __shared__ float tile[32][33];
    const float* W;
    u16* Wt;
    int N, t;
    if (bid < 1024)      { W = Wq;  Wt = WqT;  N = 1024; t = bid; }
    else if (bid < 3072) { W = Wkv; Wt = WkvT; N = 2048; t = bid - 1024; }
    else                 { W = Wo;  Wt = WoT;  N = 1024; t = bid - 3072; }
    const int sh = (N >> 11) + 5;               // 1024->5, 2048->6
    const int n0 = (t & ((1 << sh) - 1)) << 5;
    const int k0 = (t >> sh) << 5;
    const int tx = threadIdx.x & 31, ty = threadIdx.x >> 5;
#pragma unroll
    for (int i = 0; i < 32; i += 8)
      tile[ty + i][tx] = W[(size_t)(k0 + ty + i) * N + n0 + tx];
    __syncthreads();
#pragma unroll
    for (int i = 0; i < 32; i += 8)
      Wt[(size_t)(n0 + ty + i) * 1024 + k0 + tx] = f2bf(tile[tx][ty + i]);
    return;
  }
  const int NQ4 = 2097152, NKV4 = 262144, NR = 131072;
  const int stride = 2048 * 256;
  for (int u = (bid - 4096) * 256 + threadIdx.x; u < NQ4 + NKV4 + NR; u += stride) {
    if (u < NQ4) {
      const float4 v = ((const float4*)q)[u];
      ushort4 o;
      o.x = f2bf(v.x); o.y = f2bf(v.y); o.z = f2bf(v.z); o.w = f2bf(v.w);
      ((ushort4*)qb)[u] = o;
    } else if (u < NQ4 + NKV4) {
      const int i = u - NQ4;
      const float4 v = ((const float4*)kv)[i];
      ushort4 o;
      o.x = f2bf(v.x); o.y = f2bf(v.y); o.z = f2bf(v.z); o.w = f2bf(v.w);
      ((ushort4*)kvb)[i] = o;
    } else {
      const int i = u - NQ4 - NKV4;
      const int pos = i >> 5, j = i & 31;
      const float invf = expf(-(float)j * 0.28782313662425572f);  // ln(10000)/32
      float s, c;
      sincosf((float)pos * invf, &s, &c);
      csT[i] = make_float2(c, s);
    }
  }
}

// ---------------------------------------------------------------------------
// 256x128 GEMM tile core: C += A[M,1024](rows m0..m0+255) * Bt[N,1024]^T
// (rows n0..n0+127). 256 thr = 4 waves (2x2); per-wave output 128x64 =
// 8x4 frags of 16x16 (mfma 16x16x32). BK=32, K=1024, 32 K-steps.
// 3 LDS buffers (A 16KB + B 8KB each), stage 2 ahead, steady vmcnt(6)
// (6 gload_lds per thread per stage), raw s_barrier.
// 16B-chunk XOR swizzle slot = g ^ ((row>>1)&3), same K-bijection both
// operands (MFMA contraction invariant).
// Hazard: STAGE(t+2) overwrites buf[(t-1)%3]; consumer ds_reads of that
// buffer completed before the t-1 barrier (MFMA data-dep forces lgkmcnt).
__device__ __forceinline__ void gemm_core_256(
    const u16* __restrict__ A, const u16* __restrict__ Bt,
    int m0, int n0, fvec4 acc[8][4], u16* As, u16* Bs) {
  const int tid = threadIdx.x;
  const int lane = tid & 63;
  const int wv = tid >> 6, wm = wv >> 1, wn = wv & 1;

  // fragment read offsets (u16 units) within one buffer
  int a_off[8], b_off[4];
#pragma unroll
  for (int i = 0; i < 8; ++i) {
    const int rA = wm * 128 + i * 16 + (lane & 15);
    a_off[i] = rA * 32 + (((lane >> 4) ^ ((rA >> 1) & 3)) << 3);
  }
#pragma unroll
  for (int i = 0; i < 4; ++i) {
    const int rB = wn * 64 + i * 16 + (lane & 15);
    b_off[i] = rB * 32 + (((lane >> 4) ^ ((rB >> 1) & 3)) << 3);
  }

  // staging: A = 1024 chunks (16B), 4/thread; B = 512 chunks, 2/thread.
  const u16* ag[4];
  int al[4];
#pragma unroll
  for (int j = 0; j < 4; ++j) {
    const int c = tid + j * 256;
    const int r = c >> 2, g = (c & 3) ^ ((r >> 1) & 3);
    ag[j] = A + (size_t)(m0 + r) * 1024 + g * 8;
    al[j] = c * 8;
  }
  const u16* bg[2];
  int bl[2];
#pragma unroll
  for (int j = 0; j < 2; ++j) {
    const int c = tid + j * 256;
    const int r = c >> 2, g = (c & 3) ^ ((r >> 1) & 3);
    bg[j] = Bt + (size_t)(n0 + r) * 1024 + g * 8;
    bl[j] = c * 8;
  }

#define STAGE6(buf, kk)                                                      \
  do {                                                                       \
    u16* As_ = As + (buf) * 8192;                                            \
    u16* Bs_ = Bs + (buf) * 4096;                                            \
    _Pragma("unroll") for (int j = 0; j < 4; ++j)                            \
        __builtin_amdgcn_global_load_lds(                                    \
            (__attribute__((address_space(1))) void*)(ag[j] + (kk)),         \
            (__attribute__((address_space(3))) void*)(As_ + al[j]), 16, 0, 0);\
    _Pragma("unroll") for (int j = 0; j < 2; ++j)                            \
        __builtin_amdgcn_global_load_lds(                                    \
            (__attribute__((address_space(1))) void*)(bg[j] + (kk)),         \
            (__attribute__((address_space(3))) void*)(Bs_ + bl[j]), 16, 0, 0);\
  } while (0)

  // prologue: stage tiles 0 and 1 (12 loads); wait tile 0 (vmcnt(6)).
  STAGE6(0, 0);
  STAGE6(1, 32);
  asm volatile("s_waitcnt vmcnt(6)" ::: "memory");
  __builtin_amdgcn_s_barrier();

#pragma unroll
  for (int t = 0; t < 32; ++t) {
    const int k2 = t * 32 + 64;
    if (k2 < 1024) STAGE6((t + 2) % 3, k2);
    const int ca = (t % 3) * 8192, cb = (t % 3) * 4096;
    bhalf8 af[8], bfv[4];
#pragma unroll
    for (int i = 0; i < 8; ++i) af[i] = *(const bhalf8*)(As + ca + a_off[i]);
#pragma unroll
    for (int i = 0; i < 4; ++i) bfv[i] = *(const bhalf8*)(Bs + cb + b_off[i]);
    __builtin_amdgcn_s_setprio(1);
#pragma unroll
    for (int mi = 0; mi < 8; ++mi)
#pragma unroll
      for (int ni = 0; ni < 4; ++ni)
        acc[mi][ni] = __builtin_amdgcn_mfma_f32_16x16x32_bf16(
            af[mi], bfv[ni], acc[mi][ni], 0, 0, 0);
    __builtin_amdgcn_s_setprio(0);
    if (k2 < 1024) {
      asm volatile("s_waitcnt vmcnt(6)" ::: "memory");  // tile t+1 landed
    } else {
      asm volatile("s_waitcnt vmcnt(0)" ::: "memory");  // drain tail
    }
    __builtin_amdgcn_s_barrier();
  }
#undef STAGE6
}

#define GEMM_PROLOGUE()                                              \
  __shared__ __align__(16) u16 As[3 * 256 * 32];                     \
  __shared__ __align__(16) u16 Bs[3 * 128 * 32];                     \
  fvec4 acc[8][4];                                                   \
  _Pragma("unroll") for (int i = 0; i < 8; ++i)                      \
      _Pragma("unroll") for (int j = 0; j < 4; ++j)                  \
          acc[i][j] = (fvec4){0.f, 0.f, 0.f, 0.f};

// ---------------------------------------------------------------------------
// Fused GEMM1+GEMM2, 320 wgs (8 XCD chunks of 40), all co-resident (2/CU).
// role swz<256:  qh = bf16( RoPE(q @ Wq) * 0.125 )   M=8192 N=1024 (32x8)
// role swz>=256: kvl = kv @ Wkv (4x16); cols<1024 -> kh (RoPE), else vh
__global__ __launch_bounds__(256, 2) void gemm12_kernel(
    const u16* __restrict__ qA, const u16* __restrict__ WqT,
    const u16* __restrict__ kvA, const u16* __restrict__ WkvT,
    u16* __restrict__ qh, u16* __restrict__ kh, u16* __restrict__ vh,
    const int* __restrict__ qpos, const int* __restrict__ kpos,
    const float2* __restrict__ csT) {
  GEMM_PROLOGUE();
  const int swz = ((blockIdx.x & 7) * 40) + (blockIdx.x >> 3);  // bijective, 320=8*40
  const int lane = threadIdx.x & 63;
  const int wv = threadIdx.x >> 6, wm = wv >> 1, wn = wv & 1;

  if (swz < 256) {
    const int m0 = (swz >> 3) * 256, n0 = (swz & 7) * 128;
    gemm_core_256(qA, WqT, m0, n0, acc, As, Bs);
#pragma unroll
    for (int mi = 0; mi < 8; ++mi) {
#pragma unroll
      for (int r = 0; r < 4; ++r) {
        const int rowg = m0 + wm * 128 + mi * 16 + (lane >> 4) * 4 + r;
        int pos = qpos[rowg];
        pos = pos < 0 ? 0 : (pos > 4095 ? 4095 : pos);
#pragma unroll
        for (int ni = 0; ni < 2; ++ni) {
          const int j = ni * 16 + (lane & 15);
          const float2 cs = csT[pos * 32 + j];
          const float x1 = acc[mi][ni][r], x2 = acc[mi][ni + 2][r];
          const int colg = n0 + wn * 64 + ni * 16 + (lane & 15);
          qh[(size_t)rowg * 1024 + colg]      = f2bf((x1 * cs.x - x2 * cs.y) * 0.125f);
          qh[(size_t)rowg * 1024 + colg + 32] = f2bf((x2 * cs.x + x1 * cs.y) * 0.125f);
        }
      }
    }
  } else {
    const int t = swz - 256;                       // 0..63
    const int m0 = (t >> 4) * 256, n0 = (t & 15) * 128;
    gemm_core_256(kvA, WkvT, m0, n0, acc, As, Bs);
    const bool isK = (n0 + wn * 64) < 1024;
#pragma unroll
    for (int mi = 0; mi < 8; ++mi) {
#pragma unroll
      for (int r = 0; r < 4; ++r) {
        const int rowg = m0 + wm * 128 + mi * 16 + (lane >> 4) * 4 + r;  // 0..1023
        if (isK) {
          int pos = kpos[rowg & 511];
          pos = pos < 0 ? 0 : (pos > 4095 ? 4095 : pos);
#pragma unroll
          for (int ni = 0; ni < 2; ++ni) {
            const int j = ni * 16 + (lane & 15);
            const float2 cs = csT[pos * 32 + j];
            const float x1 = acc[mi][ni][r], x2 = acc[mi][ni + 2][r];
            const int colg = n0 + wn * 64 + ni * 16 + (lane & 15);
            kh[(size_t)rowg * 1024 + colg]      = f2bf(x1 * cs.x - x2 * cs.y);
            kh[(size_t)rowg * 1024 + colg + 32] = f2bf(x2 * cs.x + x1 * cs.y);
          }
        } else {
#pragma unroll
          for (int ni = 0; ni < 4; ++ni) {
            const int colg = n0 + wn * 64 + ni * 16 + (lane & 15);
            vh[(size_t)rowg * 1024 + colg - 1024] = f2bf(acc[mi][ni][r]);
          }
        }
      }
    }
  }
}

// ---------------------------------------------------------------------------
// GEMM3: out_f32 = ctx @ Wo   M=8192 N=1024, 256 wgs (32x8), all co-resident
__global__ __launch_bounds__(256, 2) void gemm_out_kernel(
    const u16* __restrict__ A, const u16* __restrict__ Bt,
    float* __restrict__ out) {
  GEMM_PROLOGUE();
  const int wg = ((blockIdx.x & 7) << 5) + (blockIdx.x >> 3);  // XCD swizzle, 256=8*32
  const int m0 = (wg >> 3) * 256, n0 = (wg & 7) * 128;
  gemm_core_256(A, Bt, m0, n0, acc, As, Bs);
  const int lane = threadIdx.x & 63;
  const int wv = threadIdx.x >> 6, wm = wv >> 1, wn = wv & 1;
#pragma unroll
  for (int mi = 0; mi < 8; ++mi) {
#pragma unroll
    for (int r = 0; r < 4; ++r) {
      const int rowg = m0 + wm * 128 + mi * 16 + (lane >> 4) * 4 + r;
#pragma unroll
      for (int ni = 0; ni < 4; ++ni) {
        const int colg = n0 + wn * 64 + ni * 16 + (lane & 15);
        out[(size_t)rowg * 1024 + colg] = acc[mi][ni][r];
      }
    }
  }
}

// ---------------------------------------------------------------------------
// Sparse attention (unchanged): k in [max(seg-4,0), seg] (<=5 keys).
__global__ __launch_bounds__(256) void attn_kernel(
    const u16* __restrict__ qh, const u16* __restrict__ kh,
    const u16* __restrict__ vh, const int* __restrict__ seg_id,
    u16* __restrict__ ctx) {
  const int lane = threadIdx.x & 63;
  const int row = (blockIdx.x * 256 + threadIdx.x) >> 6;   // 0..8191
  const int b = row >> 12;
  const int sg = seg_id[row];
  const int kmin = sg > 4 ? sg - 4 : 0;

  const u16* qp = qh + (size_t)row * 1024 + lane * 16;
  const bhalf8 qa = *(const bhalf8*)qp;
  const bhalf8 qb = *(const bhalf8*)(qp + 8);
  float qv[16];
#pragma unroll
  for (int e = 0; e < 8; ++e) {
    qv[e] = bf2f((u16)qa[e]);
    qv[8 + e] = bf2f((u16)qb[e]);
  }

  float sc[5];
  float mx = -3.0e38f;
#pragma unroll
  for (int t = 0; t < 5; ++t) {
    const int k = kmin + t;                      // always in [0,511]
    const u16* kp = kh + (size_t)((b << 9) + k) * 1024 + lane * 16;
    const bhalf8 ka = *(const bhalf8*)kp;
    const bhalf8 kb = *(const bhalf8*)(kp + 8);
    float d = 0.f;
#pragma unroll
    for (int e = 0; e < 8; ++e)
      d += qv[e] * bf2f((u16)ka[e]) + qv[8 + e] * bf2f((u16)kb[e]);
    d += __shfl_xor(d, 1);
    d += __shfl_xor(d, 2);                       // sum over 4 lanes of this head
    sc[t] = (k <= sg) ? d : -3.0e38f;
    mx = fmaxf(mx, sc[t]);
  }

  float den = 0.f;
  float o[16];
#pragma unroll
  for (int e = 0; e < 16; ++e) o[e] = 0.f;
#pragma unroll
  for (int t = 0; t < 5; ++t) {
    const float p = __expf(sc[t] - mx);          // masked -> exp(-huge) = 0
    den += p;
    const int k = kmin + t;
    const u16* vp = vh + (size_t)((b << 9) + k) * 1024 + lane * 16;
    const bhalf8 va = *(const bhalf8*)vp;
    const bhalf8 vb = *(const bhalf8*)(vp + 8);
#pragma unroll
    for (int e = 0; e < 8; ++e) {
      o[e] += p * bf2f((u16)va[e]);
      o[8 + e] += p * bf2f((u16)vb[e]);
    }
  }
  const float inv = 1.f / den;
  bhalf8 oa, ob;
#pragma unroll
  for (int e = 0; e < 8; ++e) {
    oa[e] = (short)f2bf(o[e] * inv);
    ob[e] = (short)f2bf(o[8 + e] * inv);
  }
  u16* cp = ctx + (size_t)row * 1024 + lane * 16;
  *(bhalf8*)cp = oa;
  *(bhalf8*)(cp + 8) = ob;
}

// ---------------------------------------------------------------------------
extern "C" void kernel_launch(void* const* d_in, const int* in_sizes, int n_in,
                              void* d_out, int out_size, void* d_ws, size_t ws_size,
                              hipStream_t stream) {
  const float* q   = (const float*)d_in[0];
  const float* kv  = (const float*)d_in[1];
  const int* qpos  = (const int*)d_in[2];
  const int* kpos  = (const int*)d_in[3];
  const int* seg   = (const int*)d_in[4];
  const float* Wq  = (const float*)d_in[5];
  const float* Wkv = (const float*)d_in[6];
  const float* Wo  = (const float*)d_in[7];
  float* out = (float*)d_out;

  // workspace carve-up (~66 MB total)
  char* w = (char*)d_ws;
  u16* qb    = (u16*)w; w += (size_t)8192 * 1024 * 2;
  u16* kvb   = (u16*)w; w += (size_t)1024 * 1024 * 2;
  u16* WqT   = (u16*)w; w += (size_t)1024 * 1024 * 2;
  u16* WkvT  = (u16*)w; w += (size_t)2048 * 1024 * 2;
  u16* WoT   = (u16*)w; w += (size_t)1024 * 1024 * 2;
  u16* qhB   = (u16*)w; w += (size_t)8192 * 1024 * 2;
  u16* khB   = (u16*)w; w += (size_t)1024 * 1024 * 2;
  u16* vhB   = (u16*)w; w += (size_t)1024 * 1024 * 2;
  u16* ctxB  = (u16*)w; w += (size_t)8192 * 1024 * 2;
  float2* csT = (float2*)w; w += (size_t)4096 * 32 * 8;

  prep_kernel<<<6144, 256, 0, stream>>>(Wq, Wkv, Wo, WqT, WkvT, WoT,
                                        q, qb, kv, kvb, csT);
  gemm12_kernel<<<320, 256, 0, stream>>>(qb, WqT, kvb, WkvT,
                                         qhB, khB, vhB, qpos, kpos, csT);
  attn_kernel<<<2048, 256, 0, stream>>>(qhB, khB, vhB, seg, ctxB);
  gemm_out_kernel<<<256, 256, 0, stream>>>(ctxB, WoT, out);
}